// Round 8
// baseline (17.502 us; speedup 1.0000x reference)
//
#include <hip/hip_runtime.h>
#include <math.h>

#define NC   16
#define HWSZ (128 * 128)
#define NB   16
#define TOT  (NB * NC * HWSZ)   // 4,194,304 elements per output tensor

typedef float f4 __attribute__((ext_vector_type(4)));

// Branchless erf, Abramowitz-Stegun 7.1.26, |err| <= 1.5e-7.
__device__ __forceinline__ float fast_erf(float v) {
    const float ax = fabsf(v);
    const float t  = __fdividef(1.0f, fmaf(0.3275911f, ax, 1.0f));
    float p = fmaf(1.061405429f, t, -1.453152027f);
    p = fmaf(p, t,  1.421413741f);
    p = fmaf(p, t, -0.284496736f);
    p = fmaf(p, t,  0.254829592f);
    p *= t;
    const float e = __expf(-v * v);
    return copysignf(fmaf(-p, e, 1.0f), v);
}

__global__ __launch_bounds__(256) void moe_router_kernel(
    const float* __restrict__ x, const float* __restrict__ noise,
    const float* __restrict__ gp, const float* __restrict__ wnp,
    float* __restrict__ out)
{
    const int t  = blockIdx.x * blockDim.x + threadIdx.x;  // 65536 threads
    const int sp = t << 2;              // first of 4 consecutive positions
    const int b  = sp >> 14;            // / HWSZ
    const int hw = sp & (HWSZ - 1);
    const size_t base = (size_t)b * (NC * HWSZ) + hw;

    // Per-channel state (compile-time indexed). hl[] dropped: softmax sum
    // folded online (one extra __expf/chan) to keep VGPRs moderate.
    float wg[NC][4], wn[NC][4];
    float m1[4], m2[4], ssum[4];
    int   amax[4];
    #pragma unroll
    for (int j = 0; j < 4; ++j) {
        m1[j] = -INFINITY; m2[j] = -INFINITY; ssum[j] = 0.0f; amax[j] = 0;
    }

    // Pass 1: PLAIN float4 loads (1KB/wave-instruction per stream; inputs
    // allocate in L2/L3 and stay resident across graph replays).
    #pragma unroll
    for (int c = 0; c < NC; ++c) {
        const f4 xv = *reinterpret_cast<const f4*>(x     + base + (size_t)c * HWSZ);
        const f4 nv = *reinterpret_cast<const f4*>(noise + base + (size_t)c * HWSZ);
        const float g = gp[c];
        const float w = wnp[c];
        #pragma unroll
        for (int j = 0; j < 4; ++j) {
            const float wgv = xv[j] * g;
            const float z   = xv[j] * w;
            const float spv = fmaxf(z, 0.0f) + __logf(1.0f + __expf(-fabsf(z)));
            const float h   = __builtin_fmaf(nv[j], spv, wgv);
            wg[c][j] = wgv;
            wn[c][j] = spv;
            const float m1n = fmaxf(m1[j], h);
            // online softmax sum; __expf(-inf)=0 handles c==0 cleanly
            ssum[j] = __builtin_fmaf(ssum[j], __expf(m1[j] - m1n),
                                     __expf(h - m1n));
            amax[j] = (h > m1[j]) ? c : amax[j];   // strict > : first occurrence
            m2[j]   = fmaxf(m2[j], fminf(m1[j], h));
            m1[j]   = m1n;
        }
    }

    float ginv[4];
    #pragma unroll
    for (int j = 0; j < 4; ++j)
        ginv[j] = __fdividef(1.0f, ssum[j]);

    // Pass 2: NT float4 stores (1KB/wave-instruction per stream; the one-shot
    // 33.5MB output stream bypasses L2 without evicting the cached inputs).
    #pragma unroll
    for (int c = 0; c < NC; ++c) {
        f4 gout, lout;
        #pragma unroll
        for (int j = 0; j < 4; ++j) {
            const bool  top = (c == amax[j]);
            const float mex = top ? m2[j] : m1[j];
            lout[j] = fast_erf(__fdividef(wg[c][j] - mex, wn[c][j]));
            gout[j] = top ? ginv[j] : 0.0f;
        }
        __builtin_nontemporal_store(gout,
            reinterpret_cast<f4*>(out       + base + (size_t)c * HWSZ));
        __builtin_nontemporal_store(lout,
            reinterpret_cast<f4*>(out + TOT + base + (size_t)c * HWSZ));
    }
}

extern "C" void kernel_launch(void* const* d_in, const int* in_sizes, int n_in,
                              void* d_out, int out_size, void* d_ws, size_t ws_size,
                              hipStream_t stream) {
    const float* x     = (const float*)d_in[0];
    const float* noise = (const float*)d_in[1];
    const float* gp    = (const float*)d_in[2];
    const float* wnp   = (const float*)d_in[3];
    float* out = (float*)d_out;

    const int threads = (NB * HWSZ) / 4;  // 65536 threads, 4 positions each
    const int block   = 256;
    const int grid    = threads / block;  // 256 blocks
    moe_router_kernel<<<grid, block, 0, stream>>>(x, noise, gp, wnp, out);
}

// Round 9
// 16.207 us; speedup vs baseline: 1.0799x; 1.0799x over previous
//
#include <hip/hip_runtime.h>
#include <math.h>

#define NC   16
#define HWSZ (128 * 128)
#define NB   16
#define TOT  (NB * NC * HWSZ)    // 4,194,304 elements per output tensor
#define HALF (NB * HWSZ / 2)     // 131072 positions per half

// Branchless erf, Abramowitz-Stegun 7.1.26, |err| <= 1.5e-7.
__device__ __forceinline__ float fast_erf(float v) {
    const float ax = fabsf(v);
    const float t  = __fdividef(1.0f, fmaf(0.3275911f, ax, 1.0f));
    float p = fmaf(1.061405429f, t, -1.453152027f);
    p = fmaf(p, t,  1.421413741f);
    p = fmaf(p, t, -0.284496736f);
    p = fmaf(p, t,  0.254829592f);
    p *= t;
    const float e = __expf(-v * v);
    return copysignf(fmaf(-p, e, 1.0f), v);
}

__global__ __launch_bounds__(256) void moe_router_kernel(
    const float* __restrict__ x, const float* __restrict__ noise,
    const float* __restrict__ gp, const float* __restrict__ wnp,
    float* __restrict__ out)
{
    const int t = blockIdx.x * blockDim.x + threadIdx.x;   // 131072 threads

    // Two positions per thread, one from each batch-half: loads stay fully
    // coalesced (consecutive lanes -> consecutive addresses in both halves).
    const int p0 = t;
    const int p1 = t + HALF;
    const size_t base0 = (size_t)(p0 >> 14) * (NC * HWSZ) + (p0 & (HWSZ - 1));
    const size_t base1 = (size_t)(p1 >> 14) * (NC * HWSZ) + (p1 & (HWSZ - 1));

    // ---------------- pass 1 for p0 (loads + Hlogits + top2/argmax) -------
    float wg0[NC], wn0[NC], hl0[NC];
    float m1_0 = -INFINITY, m2_0 = -INFINITY;
    int   am_0 = 0;
    #pragma unroll
    for (int c = 0; c < NC; ++c) {
        const float xv = x[base0 + (size_t)c * HWSZ];
        const float nv = noise[base0 + (size_t)c * HWSZ];
        const float wgv = xv * gp[c];
        const float z   = xv * wnp[c];
        const float spv = fmaxf(z, 0.0f) + __logf(1.0f + __expf(-fabsf(z)));
        const float h   = __builtin_fmaf(nv, spv, wgv);
        wg0[c] = wgv; wn0[c] = spv; hl0[c] = h;
        am_0 = (h > m1_0) ? c : am_0;          // strict > : first occurrence
        m2_0 = fmaxf(m2_0, fminf(m1_0, h));
        m1_0 = fmaxf(m1_0, h);
    }

    // ---------------- issue p1 loads (no dep on p0 stores; stay in flight
    // while p0's exp/erf/store phase executes) ---------------------------
    float xv1[NC], nv1[NC];
    #pragma unroll
    for (int c = 0; c < NC; ++c) {
        xv1[c] = x[base1 + (size_t)c * HWSZ];
        nv1[c] = noise[base1 + (size_t)c * HWSZ];
    }

    // ---------------- pass 2+3 for p0 (softmax denom, outputs) ------------
    {
        float ssum = 0.0f;
        #pragma unroll
        for (int c = 0; c < NC; ++c)
            ssum += __expf(hl0[c] - m1_0);
        const float ginv = __fdividef(1.0f, ssum);
        #pragma unroll
        for (int c = 0; c < NC; ++c) {
            const bool  top = (c == am_0);
            const float mex = top ? m2_0 : m1_0;
            const float ll  = fast_erf(__fdividef(wg0[c] - mex, wn0[c]));
            __builtin_nontemporal_store(top ? ginv : 0.0f,
                                        out + base0 + (size_t)c * HWSZ);
            __builtin_nontemporal_store(ll, out + TOT + base0 + (size_t)c * HWSZ);
        }
    }

    // ---------------- pass 1 for p1 (register-resident inputs) ------------
    float wg1[NC], wn1[NC], hl1[NC];
    float m1_1 = -INFINITY, m2_1 = -INFINITY;
    int   am_1 = 0;
    #pragma unroll
    for (int c = 0; c < NC; ++c) {
        const float wgv = xv1[c] * gp[c];
        const float z   = xv1[c] * wnp[c];
        const float spv = fmaxf(z, 0.0f) + __logf(1.0f + __expf(-fabsf(z)));
        const float h   = __builtin_fmaf(nv1[c], spv, wgv);
        wg1[c] = wgv; wn1[c] = spv; hl1[c] = h;
        am_1 = (h > m1_1) ? c : am_1;
        m2_1 = fmaxf(m2_1, fminf(m1_1, h));
        m1_1 = fmaxf(m1_1, h);
    }

    // ---------------- pass 2+3 for p1 -------------------------------------
    {
        float ssum = 0.0f;
        #pragma unroll
        for (int c = 0; c < NC; ++c)
            ssum += __expf(hl1[c] - m1_1);
        const float ginv = __fdividef(1.0f, ssum);
        #pragma unroll
        for (int c = 0; c < NC; ++c) {
            const bool  top = (c == am_1);
            const float mex = top ? m2_1 : m1_1;
            const float ll  = fast_erf(__fdividef(wg1[c] - mex, wn1[c]));
            __builtin_nontemporal_store(top ? ginv : 0.0f,
                                        out + base1 + (size_t)c * HWSZ);
            __builtin_nontemporal_store(ll, out + TOT + base1 + (size_t)c * HWSZ);
        }
    }
}

extern "C" void kernel_launch(void* const* d_in, const int* in_sizes, int n_in,
                              void* d_out, int out_size, void* d_ws, size_t ws_size,
                              hipStream_t stream) {
    const float* x     = (const float*)d_in[0];
    const float* noise = (const float*)d_in[1];
    const float* gp    = (const float*)d_in[2];
    const float* wnp   = (const float*)d_in[3];
    float* out = (float*)d_out;

    const int threads = HALF;             // 131072 threads, 2 positions each
    const int block   = 256;
    const int grid    = threads / block;  // 512 blocks, 8 waves/CU
    moe_router_kernel<<<grid, block, 0, stream>>>(x, noise, gp, wnp, out);
}

// Round 10
// 15.674 us; speedup vs baseline: 1.1166x; 1.0340x over previous
//
#include <hip/hip_runtime.h>
#include <math.h>

#define NC   16
#define HWSZ (128 * 128)
#define NB   16
#define TOT  (NB * NC * HWSZ)   // 4,194,304 elements per output tensor

typedef float f2 __attribute__((ext_vector_type(2)));

// Branchless erf, Abramowitz-Stegun 7.1.26, |err| <= 1.5e-7.
__device__ __forceinline__ float fast_erf(float v) {
    const float ax = fabsf(v);
    const float t  = __fdividef(1.0f, fmaf(0.3275911f, ax, 1.0f));
    float p = fmaf(1.061405429f, t, -1.453152027f);
    p = fmaf(p, t,  1.421413741f);
    p = fmaf(p, t, -0.284496736f);
    p = fmaf(p, t,  0.254829592f);
    p *= t;
    const float e = __expf(-v * v);
    return copysignf(fmaf(-p, e, 1.0f), v);
}

__global__ __launch_bounds__(256) void moe_router_kernel(
    const float* __restrict__ x, const float* __restrict__ noise,
    const float* __restrict__ gp, const float* __restrict__ wnp,
    float* __restrict__ out)
{
    const int t  = blockIdx.x * blockDim.x + threadIdx.x;  // 131072 threads
    const int sp = t << 1;              // 2 consecutive positions
    const int b  = sp >> 14;            // / HWSZ
    const int hw = sp & (HWSZ - 1);
    const size_t base = (size_t)b * (NC * HWSZ) + hw;

    // Per-channel state (compile-time indexed). Softmax sum folded online
    // (one extra __expf/chan) so hl[] isn't stored -> ~110 VGPRs, no spill.
    float wg[NC][2], wn[NC][2];
    float m1[2], m2[2], ssum[2];
    int   amax[2];
    #pragma unroll
    for (int j = 0; j < 2; ++j) {
        m1[j] = -INFINITY; m2[j] = -INFINITY; ssum[j] = 0.0f; amax[j] = 0;
    }

    // Pass 1: PLAIN float2 loads (512B per wave-instruction per stream;
    // inputs allocate in L2/L3 and stay resident across graph replays).
    #pragma unroll
    for (int c = 0; c < NC; ++c) {
        const f2 xv = *reinterpret_cast<const f2*>(x     + base + (size_t)c * HWSZ);
        const f2 nv = *reinterpret_cast<const f2*>(noise + base + (size_t)c * HWSZ);
        const float g = gp[c];
        const float w = wnp[c];
        #pragma unroll
        for (int j = 0; j < 2; ++j) {
            const float wgv = xv[j] * g;
            const float z   = xv[j] * w;
            const float spv = fmaxf(z, 0.0f) + __logf(1.0f + __expf(-fabsf(z)));
            const float h   = __builtin_fmaf(nv[j], spv, wgv);
            wg[c][j] = wgv;
            wn[c][j] = spv;
            const float m1n = fmaxf(m1[j], h);
            // online softmax sum; __expf(-inf)=0 handles c==0 cleanly
            ssum[j] = __builtin_fmaf(ssum[j], __expf(m1[j] - m1n),
                                     __expf(h - m1n));
            amax[j] = (h > m1[j]) ? c : amax[j];   // strict > : first occurrence
            m2[j]   = fmaxf(m2[j], fminf(m1[j], h));
            m1[j]   = m1n;
        }
    }

    float ginv[2];
    #pragma unroll
    for (int j = 0; j < 2; ++j)
        ginv[j] = __fdividef(1.0f, ssum[j]);

    // Pass 2: NT float2 stores (512B per wave-instruction per stream; the
    // one-shot output stream bypasses L2 without evicting cached inputs).
    #pragma unroll
    for (int c = 0; c < NC; ++c) {
        f2 gout, lout;
        #pragma unroll
        for (int j = 0; j < 2; ++j) {
            const bool  top = (c == amax[j]);
            const float mex = top ? m2[j] : m1[j];
            lout[j] = fast_erf(__fdividef(wg[c][j] - mex, wn[c][j]));
            gout[j] = top ? ginv[j] : 0.0f;
        }
        __builtin_nontemporal_store(gout,
            reinterpret_cast<f2*>(out       + base + (size_t)c * HWSZ));
        __builtin_nontemporal_store(lout,
            reinterpret_cast<f2*>(out + TOT + base + (size_t)c * HWSZ));
    }
}

extern "C" void kernel_launch(void* const* d_in, const int* in_sizes, int n_in,
                              void* d_out, int out_size, void* d_ws, size_t ws_size,
                              hipStream_t stream) {
    const float* x     = (const float*)d_in[0];
    const float* noise = (const float*)d_in[1];
    const float* gp    = (const float*)d_in[2];
    const float* wnp   = (const float*)d_in[3];
    float* out = (float*)d_out;

    const int threads = (NB * HWSZ) / 2;  // 131072 threads, 2 positions each
    const int block   = 256;
    const int grid    = threads / block;  // 512 blocks, 8 waves/CU
    moe_router_kernel<<<grid, block, 0, stream>>>(x, noise, gp, wnp, out);
}